// Round 5
// baseline (67.856 us; speedup 1.0000x reference)
//
#include <hip/hip_runtime.h>
#include <hip/hip_bf16.h>

#define NUM_NODES 16384
#define NPG 8           // nodes per graph
#define NUM_EDGES 14336
#define EPG 7           // edges per graph
#define NUM_RELS 64
#define DIM 128
#define BATCH 2048
#define EPS 1e-8f

#define CAP 512         // max edges per relation (avg 224; P(>512) astronomically small)
#define SPLITS 8        // edge blocks per relation
#define TILE 32         // rows per tile
#define DCH 32          // d-chunk staged in LDS
#define EDGE_BLOCKS (NUM_RELS * SPLITS)          // 512
#define ROOT_BLOCKS (NUM_NODES / TILE)           // 512

// ws layout (bytes)
#define CNT_OFF   0u
#define ELIST_OFF 256u
#define MSG_OFF   (256u + (unsigned)(NUM_RELS * CAP * 4))                 // 131328
#define ROOTP_OFF (MSG_OFF + (unsigned)(NUM_EDGES * DIM * 4))            // 7471360
#define WS_NEEDED ((size_t)ROOTP_OFF + (size_t)NUM_NODES * DIM * 4)      // ~15.1 MB

// ---------------- kernel 1: bucket edges by relation ----------------
__global__ __launch_bounds__(256) void build_lists_kernel(
    const int* __restrict__ edge_type, int* __restrict__ cnt, int* __restrict__ elist)
{
    __shared__ int lcnt;
    const int r = blockIdx.x;
    if (threadIdx.x == 0) lcnt = 0;
    __syncthreads();
    for (int e = threadIdx.x; e < NUM_EDGES; e += 256) {
        if (edge_type[e] == r) {
            int p = atomicAdd(&lcnt, 1);
            if (p < CAP) elist[r * CAP + p] = e;
        }
    }
    __syncthreads();
    if (threadIdx.x == 0) cnt[r] = min(lcnt, CAP);
}

// ---------------- kernel 2: relation-major tiled matmul ----------------
// Computes msg[e][:] = x[src[e]] @ basis[rel] for all edges (grouped by rel),
// and rootp[i][:] = x[i] @ root for all nodes. Register-blocked 4 rows x 4 cols
// per thread; B staged in LDS in 32-row chunks; x rows staged in LDS per tile.
__device__ __forceinline__ void tile_mm(
    const float* __restrict__ Bg, const float* __restrict__ x,
    float (*xs)[DIM], float (*bs)[DIM],
    const int* srcs, const int* eids, int nrows,
    float* __restrict__ outbuf, int c, int rg)
{
    const int tid = threadIdx.x;

    // stage x rows: 32 rows x 128 floats = 1024 float4, 256 threads -> 4 each
    #pragma unroll
    for (int k = 0; k < 4; ++k) {
        int idx = k * 256 + tid;        // 0..1023
        int row = idx >> 5;
        int seg = idx & 31;
        float4 v = make_float4(0.f, 0.f, 0.f, 0.f);
        if (row < nrows) v = *(const float4*)(x + (size_t)srcs[row] * DIM + seg * 4);
        *(float4*)(&xs[row][seg * 4]) = v;
    }

    float4 acc[4];
    #pragma unroll
    for (int rr = 0; rr < 4; ++rr) acc[rr] = make_float4(0.f, 0.f, 0.f, 0.f);

    for (int ch = 0; ch < DIM / DCH; ++ch) {
        __syncthreads();   // xs staged (ch=0) / previous chunk's bs consumed
        // stage B chunk: 32 d-rows x 128 cols
        #pragma unroll
        for (int k = 0; k < 4; ++k) {
            int idx = k * 256 + tid;
            int dd  = idx >> 5;
            int seg = idx & 31;
            *(float4*)(&bs[dd][seg * 4]) =
                *(const float4*)(Bg + (size_t)(ch * DCH + dd) * DIM + seg * 4);
        }
        __syncthreads();
        #pragma unroll
        for (int q = 0; q < DCH / 4; ++q) {
            const float4 b0 = *(const float4*)(&bs[q * 4 + 0][c * 4]);
            const float4 b1 = *(const float4*)(&bs[q * 4 + 1][c * 4]);
            const float4 b2 = *(const float4*)(&bs[q * 4 + 2][c * 4]);
            const float4 b3 = *(const float4*)(&bs[q * 4 + 3][c * 4]);
            #pragma unroll
            for (int rr = 0; rr < 4; ++rr) {
                const float4 xv = *(const float4*)(&xs[rg * 4 + rr][ch * DCH + q * 4]);
                acc[rr].x += xv.x * b0.x + xv.y * b1.x + xv.z * b2.x + xv.w * b3.x;
                acc[rr].y += xv.x * b0.y + xv.y * b1.y + xv.z * b2.y + xv.w * b3.y;
                acc[rr].z += xv.x * b0.z + xv.y * b1.z + xv.z * b2.z + xv.w * b3.z;
                acc[rr].w += xv.x * b0.w + xv.y * b1.w + xv.z * b2.w + xv.w * b3.w;
            }
        }
    }
    // store: row rg*4+rr, cols 4c..4c+3
    #pragma unroll
    for (int rr = 0; rr < 4; ++rr) {
        int row = rg * 4 + rr;
        if (row < nrows && eids[row] >= 0) {
            *(float4*)(outbuf + (size_t)eids[row] * DIM + c * 4) = acc[rr];
        }
    }
}

__global__ __launch_bounds__(256) void matmul_kernel(
    const float* __restrict__ x, const float* __restrict__ basis,
    const float* __restrict__ root, const int* __restrict__ edge_index,
    const int* __restrict__ cnt, const int* __restrict__ elist,
    float* __restrict__ msg, float* __restrict__ rootp)
{
    __shared__ float xs[TILE][DIM];   // 16 KB
    __shared__ float bs[DCH][DIM];    // 16 KB
    __shared__ int eids[TILE];
    __shared__ int srcs[TILE];

    const int tid = threadIdx.x;
    const int c   = tid & 31;   // col group: cols 4c..4c+3
    const int rg  = tid >> 5;   // row group: rows rg*4..rg*4+3

    if (blockIdx.x < EDGE_BLOCKS) {
        const int rel   = blockIdx.x >> 3;
        const int split = blockIdx.x & (SPLITS - 1);
        const float* Bg = basis + (size_t)rel * DIM * DIM;
        const int count = cnt[rel];
        for (int t = split; t * TILE < count; t += SPLITS) {
            __syncthreads();   // protect eids/srcs against previous tile's readers
            if (tid < TILE) {
                int j = t * TILE + tid;
                if (j < count) {
                    int e = elist[rel * CAP + j];
                    eids[tid] = e;
                    srcs[tid] = edge_index[e];   // global src node id
                } else {
                    eids[tid] = -1;
                    srcs[tid] = 0;
                }
            }
            __syncthreads();
            int nrows = count - t * TILE;
            if (nrows > TILE) nrows = TILE;
            tile_mm(Bg, x, xs, bs, srcs, eids, nrows, msg, c, rg);
        }
    } else {
        const int rb   = blockIdx.x - EDGE_BLOCKS;
        const int row0 = rb * TILE;
        if (tid < TILE) {
            eids[tid] = row0 + tid;
            srcs[tid] = row0 + tid;
        }
        __syncthreads();
        tile_mm(root, x, xs, bs, srcs, eids, TILE, rootp, c, rg);
    }
}

// ---------------- kernel 3: aggregate + relu + pool + cosine ----------------
__global__ __launch_bounds__(128) void finalize_kernel(
    const float* __restrict__ rootp, const float* __restrict__ msg,
    const float* __restrict__ bias, const float* __restrict__ target,
    const int* __restrict__ edge_index, float* __restrict__ out)
{
    const int g = blockIdx.x;
    const int o = threadIdx.x;
    __shared__ float red[6];

    float acc[NPG];
    const float b = bias[o];
    #pragma unroll
    for (int n = 0; n < NPG; ++n)
        acc[n] = b + rootp[(size_t)(g * NPG + n) * DIM + o];

    const int ebase = g * EPG;
    #pragma unroll
    for (int e = 0; e < EPG; ++e) {
        const int ge  = ebase + e;
        const int dst = edge_index[NUM_EDGES + ge] - g * NPG;
        const float m = msg[(size_t)ge * DIM + o];
        #pragma unroll
        for (int n = 0; n < NPG; ++n) acc[n] += (n == dst) ? m : 0.f;
    }

    float p = 0.f;
    #pragma unroll
    for (int n = 0; n < NPG; ++n) p += fmaxf(acc[n], 0.f);

    const float t = target[(size_t)g * DIM + o];
    float num_p = p * t;
    float na_p  = p * p;
    float nb_p  = t * t;
    #pragma unroll
    for (int off = 32; off > 0; off >>= 1) {
        num_p += __shfl_down(num_p, off);
        na_p  += __shfl_down(na_p, off);
        nb_p  += __shfl_down(nb_p, off);
    }
    const int wave = o >> 6;
    const int lane = o & 63;
    if (lane == 0) {
        red[wave * 3 + 0] = num_p;
        red[wave * 3 + 1] = na_p;
        red[wave * 3 + 2] = nb_p;
    }
    __syncthreads();
    if (o == 0) {
        const float num = red[0] + red[3];
        const float na  = fmaxf(sqrtf(red[1] + red[4]), EPS);
        const float nb  = fmaxf(sqrtf(red[2] + red[5]), EPS);
        out[g] = num / (na * nb);
    }
}

// ---------------- fallback: the previous single-kernel version ----------------
__global__ __launch_bounds__(128) void rgcn_fused_kernel(
    const float* __restrict__ x, const float* __restrict__ basis,
    const float* __restrict__ root, const float* __restrict__ bias,
    const float* __restrict__ target, const int* __restrict__ edge_index,
    const int* __restrict__ edge_type, float* __restrict__ out)
{
    const int g = blockIdx.x;
    const int o = threadIdx.x;
    __shared__ float xs[NPG][DIM];
    __shared__ float red[6];
    {
        const float4* xg = reinterpret_cast<const float4*>(x + (size_t)g * NPG * DIM);
        float4* xs4 = reinterpret_cast<float4*>(&xs[0][0]);
        xs4[o] = xg[o];
        xs4[o + 128] = xg[o + 128];
    }
    __syncthreads();
    float acc[NPG];
    const float b = bias[o];
    #pragma unroll
    for (int n = 0; n < NPG; ++n) acc[n] = b;
    for (int d4 = 0; d4 < DIM / 4; ++d4) {
        const float r0 = root[(d4 * 4 + 0) * DIM + o];
        const float r1 = root[(d4 * 4 + 1) * DIM + o];
        const float r2 = root[(d4 * 4 + 2) * DIM + o];
        const float r3 = root[(d4 * 4 + 3) * DIM + o];
        #pragma unroll
        for (int n = 0; n < NPG; ++n) {
            const float4 xv = reinterpret_cast<const float4*>(&xs[n][0])[d4];
            acc[n] += xv.x * r0 + xv.y * r1 + xv.z * r2 + xv.w * r3;
        }
    }
    const int ebase = g * EPG;
    for (int e = 0; e < EPG; ++e) {
        const int ge  = ebase + e;
        const int src = edge_index[ge] - g * NPG;
        const int dst = edge_index[NUM_EDGES + ge] - g * NPG;
        const int rel = edge_type[ge];
        const float* __restrict__ B = basis + (size_t)rel * DIM * DIM;
        float m = 0.f;
        for (int d4 = 0; d4 < DIM / 4; ++d4) {
            const float4 xv = reinterpret_cast<const float4*>(&xs[src][0])[d4];
            m += xv.x * B[(d4 * 4 + 0) * DIM + o];
            m += xv.y * B[(d4 * 4 + 1) * DIM + o];
            m += xv.z * B[(d4 * 4 + 2) * DIM + o];
            m += xv.w * B[(d4 * 4 + 3) * DIM + o];
        }
        #pragma unroll
        for (int n = 0; n < NPG; ++n) acc[n] += (n == dst) ? m : 0.f;
    }
    float p = 0.f;
    #pragma unroll
    for (int n = 0; n < NPG; ++n) p += fmaxf(acc[n], 0.f);
    const float t = target[(size_t)g * DIM + o];
    float num_p = p * t, na_p = p * p, nb_p = t * t;
    #pragma unroll
    for (int off = 32; off > 0; off >>= 1) {
        num_p += __shfl_down(num_p, off);
        na_p  += __shfl_down(na_p, off);
        nb_p  += __shfl_down(nb_p, off);
    }
    const int wave = o >> 6, lane = o & 63;
    if (lane == 0) {
        red[wave * 3 + 0] = num_p;
        red[wave * 3 + 1] = na_p;
        red[wave * 3 + 2] = nb_p;
    }
    __syncthreads();
    if (o == 0) {
        const float num = red[0] + red[3];
        const float na  = fmaxf(sqrtf(red[1] + red[4]), EPS);
        const float nb  = fmaxf(sqrtf(red[2] + red[5]), EPS);
        out[g] = num / (na * nb);
    }
}

extern "C" void kernel_launch(void* const* d_in, const int* in_sizes, int n_in,
                              void* d_out, int out_size, void* d_ws, size_t ws_size,
                              hipStream_t stream) {
    const float* x          = (const float*)d_in[0];
    const float* basis      = (const float*)d_in[1];
    const float* root       = (const float*)d_in[2];
    const float* bias       = (const float*)d_in[3];
    const float* target     = (const float*)d_in[4];
    const int*   edge_index = (const int*)d_in[5];
    const int*   edge_type  = (const int*)d_in[6];
    float* out = (float*)d_out;

    if (ws_size < WS_NEEDED) {
        // not enough scratch: fall back to the verified single-kernel version
        rgcn_fused_kernel<<<BATCH, 128, 0, stream>>>(
            x, basis, root, bias, target, edge_index, edge_type, out);
        return;
    }

    char* ws = (char*)d_ws;
    int*   cnt   = (int*)(ws + CNT_OFF);
    int*   elist = (int*)(ws + ELIST_OFF);
    float* msg   = (float*)(ws + MSG_OFF);
    float* rootp = (float*)(ws + ROOTP_OFF);

    build_lists_kernel<<<NUM_RELS, 256, 0, stream>>>(edge_type, cnt, elist);
    matmul_kernel<<<EDGE_BLOCKS + ROOT_BLOCKS, 256, 0, stream>>>(
        x, basis, root, edge_index, cnt, elist, msg, rootp);
    finalize_kernel<<<BATCH, 128, 0, stream>>>(
        rootp, msg, bias, target, edge_index, out);
}

// Round 6
// 57.112 us; speedup vs baseline: 1.1881x; 1.1881x over previous
//
#include <hip/hip_runtime.h>
#include <hip/hip_fp16.h>

#define NUM_NODES 16384
#define NPG 8           // nodes per graph
#define NUM_EDGES 14336
#define EPG 7           // edges per graph
#define NUM_RELS 64
#define DIM 128
#define BATCH 2048
#define EPS 1e-8f

// packed fp16 layout: Bp[rel][d4][o] = uint2 holding half(B[rel][4*d4+0][o] .. [4*d4+3][o])
// -> one 8 B load per lane advances 4 d-steps; 64 lanes * 8 B = 512 B/wave (full width)
#define BP_ELEMS (NUM_RELS * (DIM / 4) * DIM)   // 262144 uint2 = 2 MB
#define RP_ELEMS ((DIM / 4) * DIM)              // 4096 uint2 = 32 KB
#define BP_OFF 0u
#define RP_OFF ((size_t)BP_ELEMS * 8)
#define WS_NEEDED (RP_OFF + (size_t)RP_ELEMS * 8)   // ~2.1 MB

// ---------------- kernel 1: pack basis+root fp32 -> fp16 (d-major x4) ----------------
__global__ __launch_bounds__(256) void pack_kernel(
    const float* __restrict__ basis, const float* __restrict__ root,
    uint2* __restrict__ Bp, uint2* __restrict__ Rp)
{
    int s = blockIdx.x * 256 + threadIdx.x;
    if (s < BP_ELEMS) {
        const int r   = s >> 12;          // / (32*128)
        const int rem = s & 4095;
        const int d4  = rem >> 7;
        const int o   = rem & 127;
        const float* src = basis + ((size_t)r << 14) + ((d4 << 2) * DIM) + o;
        __half2 lo = __floats2half2_rn(src[0],       src[DIM]);
        __half2 hi = __floats2half2_rn(src[2 * DIM], src[3 * DIM]);
        uint2 w;
        w.x = *reinterpret_cast<unsigned int*>(&lo);
        w.y = *reinterpret_cast<unsigned int*>(&hi);
        Bp[s] = w;
    } else {
        int s2 = s - BP_ELEMS;
        if (s2 < RP_ELEMS) {
            const int d4 = s2 >> 7;
            const int o  = s2 & 127;
            const float* src = root + ((d4 << 2) * DIM) + o;
            __half2 lo = __floats2half2_rn(src[0],       src[DIM]);
            __half2 hi = __floats2half2_rn(src[2 * DIM], src[3 * DIM]);
            uint2 w;
            w.x = *reinterpret_cast<unsigned int*>(&lo);
            w.y = *reinterpret_cast<unsigned int*>(&hi);
            Rp[s2] = w;
        }
    }
}

// ---------------- kernel 2: fused per-graph RGCN + pool + cosine (fp16 B stream) ----------------
__global__ __launch_bounds__(128) void rgcn_fused_fp16b_kernel(
    const float* __restrict__ x,
    const uint2* __restrict__ Bp,
    const uint2* __restrict__ Rp,
    const float* __restrict__ bias,
    const float* __restrict__ target,
    const int* __restrict__ edge_index,
    const int* __restrict__ edge_type,
    float* __restrict__ out)
{
    const int g = blockIdx.x;
    const int o = threadIdx.x;  // 0..127 (output dim)

    __shared__ float xs[NPG][DIM];   // 4 KB
    __shared__ float red[6];

    // stage x rows: 1024 floats = 256 float4
    {
        const float4* xg = reinterpret_cast<const float4*>(x + (size_t)g * NPG * DIM);
        float4* xs4 = reinterpret_cast<float4*>(&xs[0][0]);
        xs4[o]       = xg[o];
        xs4[o + 128] = xg[o + 128];
    }
    __syncthreads();

    float acc[NPG];
    {
        const float b = bias[o];
        #pragma unroll
        for (int n = 0; n < NPG; ++n) acc[n] = b;
    }

    // root part: one packed column load serves all 8 nodes
    #pragma unroll 4
    for (int d4 = 0; d4 < DIM / 4; ++d4) {
        const uint2 w = Rp[(d4 << 7) + o];
        const float2 f01 = __half22float2(*reinterpret_cast<const __half2*>(&w.x));
        const float2 f23 = __half22float2(*reinterpret_cast<const __half2*>(&w.y));
        #pragma unroll
        for (int n = 0; n < NPG; ++n) {
            const float4 xv = *reinterpret_cast<const float4*>(&xs[n][d4 << 2]);
            acc[n] += xv.x * f01.x + xv.y * f01.y + xv.z * f23.x + xv.w * f23.y;
        }
    }

    // edge part
    {
        const int ebase = g * EPG;
        for (int e = 0; e < EPG; ++e) {
            const int ge  = ebase + e;
            const int src = edge_index[ge] - g * NPG;
            const int dst = edge_index[NUM_EDGES + ge] - g * NPG;
            const int rel = edge_type[ge];
            const uint2* __restrict__ B = Bp + ((size_t)rel << 12);
            float m = 0.f;
            #pragma unroll 8
            for (int d4 = 0; d4 < DIM / 4; ++d4) {
                const uint2 w = B[(d4 << 7) + o];
                const float2 f01 = __half22float2(*reinterpret_cast<const __half2*>(&w.x));
                const float2 f23 = __half22float2(*reinterpret_cast<const __half2*>(&w.y));
                const float4 xv = *reinterpret_cast<const float4*>(&xs[src][d4 << 2]);
                m += xv.x * f01.x + xv.y * f01.y + xv.z * f23.x + xv.w * f23.y;
            }
            #pragma unroll
            for (int n = 0; n < NPG; ++n) acc[n] += (n == dst) ? m : 0.f;
        }
    }

    // relu + pool
    float p = 0.f;
    #pragma unroll
    for (int n = 0; n < NPG; ++n) p += fmaxf(acc[n], 0.f);

    // cosine vs target
    const float t = target[(size_t)g * DIM + o];
    float num_p = p * t, na_p = p * p, nb_p = t * t;
    #pragma unroll
    for (int off = 32; off > 0; off >>= 1) {
        num_p += __shfl_down(num_p, off);
        na_p  += __shfl_down(na_p, off);
        nb_p  += __shfl_down(nb_p, off);
    }
    const int wave = o >> 6, lane = o & 63;
    if (lane == 0) {
        red[wave * 3 + 0] = num_p;
        red[wave * 3 + 1] = na_p;
        red[wave * 3 + 2] = nb_p;
    }
    __syncthreads();
    if (o == 0) {
        const float num = red[0] + red[3];
        const float na  = fmaxf(sqrtf(red[1] + red[4]), EPS);
        const float nb  = fmaxf(sqrtf(red[2] + red[5]), EPS);
        out[g] = num / (na * nb);
    }
}

// ---------------- fallback: verified fp32 single-kernel version ----------------
__global__ __launch_bounds__(128) void rgcn_fused_kernel(
    const float* __restrict__ x, const float* __restrict__ basis,
    const float* __restrict__ root, const float* __restrict__ bias,
    const float* __restrict__ target, const int* __restrict__ edge_index,
    const int* __restrict__ edge_type, float* __restrict__ out)
{
    const int g = blockIdx.x;
    const int o = threadIdx.x;
    __shared__ float xs[NPG][DIM];
    __shared__ float red[6];
    {
        const float4* xg = reinterpret_cast<const float4*>(x + (size_t)g * NPG * DIM);
        float4* xs4 = reinterpret_cast<float4*>(&xs[0][0]);
        xs4[o] = xg[o];
        xs4[o + 128] = xg[o + 128];
    }
    __syncthreads();
    float acc[NPG];
    const float b = bias[o];
    #pragma unroll
    for (int n = 0; n < NPG; ++n) acc[n] = b;
    for (int d4 = 0; d4 < DIM / 4; ++d4) {
        const float r0 = root[(d4 * 4 + 0) * DIM + o];
        const float r1 = root[(d4 * 4 + 1) * DIM + o];
        const float r2 = root[(d4 * 4 + 2) * DIM + o];
        const float r3 = root[(d4 * 4 + 3) * DIM + o];
        #pragma unroll
        for (int n = 0; n < NPG; ++n) {
            const float4 xv = reinterpret_cast<const float4*>(&xs[n][0])[d4];
            acc[n] += xv.x * r0 + xv.y * r1 + xv.z * r2 + xv.w * r3;
        }
    }
    const int ebase = g * EPG;
    for (int e = 0; e < EPG; ++e) {
        const int ge  = ebase + e;
        const int src = edge_index[ge] - g * NPG;
        const int dst = edge_index[NUM_EDGES + ge] - g * NPG;
        const int rel = edge_type[ge];
        const float* __restrict__ B = basis + (size_t)rel * DIM * DIM;
        float m = 0.f;
        for (int d4 = 0; d4 < DIM / 4; ++d4) {
            const float4 xv = reinterpret_cast<const float4*>(&xs[src][0])[d4];
            m += xv.x * B[(d4 * 4 + 0) * DIM + o];
            m += xv.y * B[(d4 * 4 + 1) * DIM + o];
            m += xv.z * B[(d4 * 4 + 2) * DIM + o];
            m += xv.w * B[(d4 * 4 + 3) * DIM + o];
        }
        #pragma unroll
        for (int n = 0; n < NPG; ++n) acc[n] += (n == dst) ? m : 0.f;
    }
    float p = 0.f;
    #pragma unroll
    for (int n = 0; n < NPG; ++n) p += fmaxf(acc[n], 0.f);
    const float t = target[(size_t)g * DIM + o];
    float num_p = p * t, na_p = p * p, nb_p = t * t;
    #pragma unroll
    for (int off = 32; off > 0; off >>= 1) {
        num_p += __shfl_down(num_p, off);
        na_p  += __shfl_down(na_p, off);
        nb_p  += __shfl_down(nb_p, off);
    }
    const int wave = o >> 6, lane = o & 63;
    if (lane == 0) {
        red[wave * 3 + 0] = num_p;
        red[wave * 3 + 1] = na_p;
        red[wave * 3 + 2] = nb_p;
    }
    __syncthreads();
    if (o == 0) {
        const float num = red[0] + red[3];
        const float na  = fmaxf(sqrtf(red[1] + red[4]), EPS);
        const float nb  = fmaxf(sqrtf(red[2] + red[5]), EPS);
        out[g] = num / (na * nb);
    }
}

extern "C" void kernel_launch(void* const* d_in, const int* in_sizes, int n_in,
                              void* d_out, int out_size, void* d_ws, size_t ws_size,
                              hipStream_t stream) {
    const float* x          = (const float*)d_in[0];
    const float* basis      = (const float*)d_in[1];
    const float* root       = (const float*)d_in[2];
    const float* bias       = (const float*)d_in[3];
    const float* target     = (const float*)d_in[4];
    const int*   edge_index = (const int*)d_in[5];
    const int*   edge_type  = (const int*)d_in[6];
    float* out = (float*)d_out;

    if (ws_size < WS_NEEDED) {
        rgcn_fused_kernel<<<BATCH, 128, 0, stream>>>(
            x, basis, root, bias, target, edge_index, edge_type, out);
        return;
    }

    uint2* Bp = (uint2*)((char*)d_ws + BP_OFF);
    uint2* Rp = (uint2*)((char*)d_ws + RP_OFF);

    const int pack_total = BP_ELEMS + RP_ELEMS;
    pack_kernel<<<(pack_total + 255) / 256, 256, 0, stream>>>(basis, root, Bp, Rp);
    rgcn_fused_fp16b_kernel<<<BATCH, 128, 0, stream>>>(
        x, Bp, Rp, bias, target, edge_index, edge_type, out);
}

// Round 7
// 50.558 us; speedup vs baseline: 1.3421x; 1.1296x over previous
//
#include <hip/hip_runtime.h>

#define NUM_NODES 16384
#define NPG 8
#define NUM_EDGES 14336
#define EPG 7
#define NUM_RELS 64
#define DIM 128
#define BATCH 2048
#define EPS 1e-8f

#define CAP 512                      // max edges/relation (mean 224, sd ~15; 512 = +19 sigma)
#define EDGE_BLOCKS (NUM_RELS * 8)   // 8 parts x 64 rows = CAP coverage
#define ROOT_BLOCKS (NUM_NODES / 64) // 256

using f16x8 = __attribute__((ext_vector_type(8))) _Float16;
using f32x4 = __attribute__((ext_vector_type(4))) float;

// ---- ws layout (bytes); total 14,319,872 <= 15.9MB verified available ----
#define XH_OFF  0u
#define BH_OFF  4194304u                  // xh: 16384*128*2
#define CNT_OFF 6324224u                  // Bh: 65*128*128*2 (rel 64 = root)
#define EL_OFF  6324480u
#define MSG_OFF 6455552u                  // elist: 64*512*4
#define RTP_OFF 10125568u                 // msg_h: 14336*128*2
#define WS_NEEDED 14319872u               // rootp_h: 16384*128*2

// ---------------- kernel 1: x fp32 -> fp16 ----------------
__global__ __launch_bounds__(256) void cvt_x_kernel(
    const float* __restrict__ x, _Float16* __restrict__ xh)
{
    const int idx = blockIdx.x * 256 + threadIdx.x;   // 262144 total, 8 elems each
    const float4 u = ((const float4*)x)[idx * 2];
    const float4 v = ((const float4*)x)[idx * 2 + 1];
    f16x8 o;
    o[0] = (_Float16)u.x; o[1] = (_Float16)u.y; o[2] = (_Float16)u.z; o[3] = (_Float16)u.w;
    o[4] = (_Float16)v.x; o[5] = (_Float16)v.y; o[6] = (_Float16)v.z; o[7] = (_Float16)v.w;
    *(f16x8*)(xh + (size_t)idx * 8) = o;
}

// ---------------- kernel 2: basis/root fp32 [d][o] -> fp16 col-major [o][d] ----------------
__global__ __launch_bounds__(256) void pack_b_kernel(
    const float* __restrict__ basis, const float* __restrict__ root,
    _Float16* __restrict__ Bh)
{
    __shared__ _Float16 Tl[DIM * DIM];   // 32 KB, row-major [d][o]
    const int r = blockIdx.x;            // 0..64 (64 = root)
    const int tid = threadIdx.x;
    const float* src = (r < NUM_RELS) ? (basis + ((size_t)r << 14)) : root;

    #pragma unroll
    for (int i = 0; i < 8; ++i) {
        int g8 = i * 256 + tid;          // group of 8 f32
        const float4 a = ((const float4*)src)[g8 * 2];
        const float4 b = ((const float4*)src)[g8 * 2 + 1];
        f16x8 o;
        o[0] = (_Float16)a.x; o[1] = (_Float16)a.y; o[2] = (_Float16)a.z; o[3] = (_Float16)a.w;
        o[4] = (_Float16)b.x; o[5] = (_Float16)b.y; o[6] = (_Float16)b.z; o[7] = (_Float16)b.w;
        *(f16x8*)(&Tl[g8 * 8]) = o;
    }
    __syncthreads();
    // transposed write: Bh[r][o][d]
    #pragma unroll
    for (int i = 0; i < 8; ++i) {
        int chunk = i * 256 + tid;       // 2048 chunks of 8 d-values
        int o = chunk >> 4;
        int db = chunk & 15;
        f16x8 v;
        #pragma unroll
        for (int u = 0; u < 8; ++u) v[u] = Tl[(db * 8 + u) * DIM + o];
        *(f16x8*)(Bh + ((size_t)r << 14) + o * DIM + db * 8) = v;
    }
}

// ---------------- kernel 3: bucket edges by relation ----------------
__global__ __launch_bounds__(256) void build_lists_kernel(
    const int* __restrict__ edge_type, int* __restrict__ cnt, int* __restrict__ elist)
{
    __shared__ int lcnt;
    const int r = blockIdx.x;
    if (threadIdx.x == 0) lcnt = 0;
    __syncthreads();
    for (int e = threadIdx.x; e < NUM_EDGES; e += 256) {
        if (edge_type[e] == r) {
            int p = atomicAdd(&lcnt, 1);
            if (p < CAP) elist[r * CAP + p] = e;
        }
    }
    __syncthreads();
    if (threadIdx.x == 0) cnt[r] = min(lcnt, CAP);
}

// ---------------- kernel 4: MFMA GEMM (edge msgs + root) ----------------
// Block: 256 thr = 4 waves, one 64-row strip. B (128x128 f16, col-major [col][k])
// staged in LDS with 16B-chunk XOR swizzle: chunk' = chunk ^ ((chunk>>4)&7).
// Wave w: rows w*16..+15. A-frag: lane=(q,l15): row l15, k = kb*32+q*8 (+0..7).
// B-frag: col l15(+16*ct), same k. C: row q*4+j, col l15 (m89-verified layout).
__global__ __launch_bounds__(256) void gemm_kernel(
    const _Float16* __restrict__ xh, const _Float16* __restrict__ Bh,
    const int* __restrict__ edge_index,
    const int* __restrict__ cnt, const int* __restrict__ elist,
    _Float16* __restrict__ msg_h, _Float16* __restrict__ rootp_h)
{
    __shared__ _Float16 Bl[DIM * DIM];   // 32 KB
    __shared__ int smeta[128];           // [0:64) src row, [64:128) out row id (-1 = skip)

    const int bid = blockIdx.x;
    const int tid = threadIdx.x;
    const bool isEdge = bid < EDGE_BLOCKS;
    const _Float16* Bg;

    if (isEdge) {
        const int rel = bid >> 3;
        const int part = bid & 7;
        const int c = cnt[rel];
        const int row0 = part * 64;
        if (row0 >= c) return;           // uniform exit before any barrier
        Bg = Bh + ((size_t)rel << 14);
        if (tid < 64) {
            int j = row0 + tid;
            if (j < c) {
                int e = elist[rel * CAP + j];
                smeta[tid] = edge_index[e];     // global src node
                smeta[64 + tid] = e;
            } else {
                smeta[tid] = 0;
                smeta[64 + tid] = -1;
            }
        }
    } else {
        const int row0 = (bid - EDGE_BLOCKS) * 64;
        Bg = Bh + ((size_t)NUM_RELS << 14);
        if (tid < 64) {
            smeta[tid] = row0 + tid;
            smeta[64 + tid] = row0 + tid;
        }
    }

    // stage B: 2048 16B-chunks, swizzled
    #pragma unroll
    for (int i = 0; i < 8; ++i) {
        int c16 = i * 256 + tid;
        int cs = c16 ^ ((c16 >> 4) & 7);
        *(f16x8*)(&Bl[cs * 8]) = *(const f16x8*)(Bg + c16 * 8);
    }
    __syncthreads();

    const int lane = tid & 63;
    const int w = tid >> 6;
    const int l15 = lane & 15;
    const int q = lane >> 4;

    // A fragments: 4 k-blocks of 16B from the gathered x row
    const int src = smeta[w * 16 + l15];
    const _Float16* xrow = xh + ((size_t)src << 7) + q * 8;
    f16x8 a[4];
    #pragma unroll
    for (int kb = 0; kb < 4; ++kb) a[kb] = *(const f16x8*)(xrow + kb * 32);

    f32x4 acc[8];
    #pragma unroll
    for (int ct = 0; ct < 8; ++ct) acc[ct] = (f32x4){0.f, 0.f, 0.f, 0.f};

    #pragma unroll
    for (int ct = 0; ct < 8; ++ct) {
        const int col = ct * 16 + l15;
        #pragma unroll
        for (int kb = 0; kb < 4; ++kb) {
            int chunk = col * 16 + kb * 4 + q;
            int cs = chunk ^ (col & 7);
            f16x8 b = *(const f16x8*)(&Bl[cs * 8]);
            acc[ct] = __builtin_amdgcn_mfma_f32_16x16x32_f16(a[kb], b, acc[ct], 0, 0, 0);
        }
    }

    _Float16* outb = isEdge ? msg_h : rootp_h;
    #pragma unroll
    for (int j = 0; j < 4; ++j) {
        const int r = w * 16 + q * 4 + j;
        const int oid = smeta[64 + r];
        if (oid >= 0) {
            #pragma unroll
            for (int ct = 0; ct < 8; ++ct) {
                outb[((size_t)oid << 7) + ct * 16 + l15] = (_Float16)acc[ct][j];
            }
        }
    }
}

// ---------------- kernel 5: aggregate + relu + pool + cosine ----------------
__global__ __launch_bounds__(128) void finalize_kernel(
    const _Float16* __restrict__ rootp_h, const _Float16* __restrict__ msg_h,
    const float* __restrict__ bias, const float* __restrict__ target,
    const int* __restrict__ edge_index, float* __restrict__ out)
{
    const int g = blockIdx.x;
    const int o = threadIdx.x;
    __shared__ float red[6];

    float acc[NPG];
    const float b = bias[o];
    #pragma unroll
    for (int n = 0; n < NPG; ++n)
        acc[n] = b + (float)rootp_h[((size_t)(g * NPG + n) << 7) + o];

    const int ebase = g * EPG;
    #pragma unroll
    for (int e = 0; e < EPG; ++e) {
        const int ge  = ebase + e;
        const int dst = edge_index[NUM_EDGES + ge] - g * NPG;
        const float m = (float)msg_h[((size_t)ge << 7) + o];
        #pragma unroll
        for (int n = 0; n < NPG; ++n) acc[n] += (n == dst) ? m : 0.f;
    }

    float p = 0.f;
    #pragma unroll
    for (int n = 0; n < NPG; ++n) p += fmaxf(acc[n], 0.f);

    const float t = target[(size_t)g * DIM + o];
    float num_p = p * t, na_p = p * p, nb_p = t * t;
    #pragma unroll
    for (int off = 32; off > 0; off >>= 1) {
        num_p += __shfl_down(num_p, off);
        na_p  += __shfl_down(na_p, off);
        nb_p  += __shfl_down(nb_p, off);
    }
    const int wave = o >> 6, lane = o & 63;
    if (lane == 0) {
        red[wave * 3 + 0] = num_p;
        red[wave * 3 + 1] = na_p;
        red[wave * 3 + 2] = nb_p;
    }
    __syncthreads();
    if (o == 0) {
        const float num = red[0] + red[3];
        const float na  = fmaxf(sqrtf(red[1] + red[4]), EPS);
        const float nb  = fmaxf(sqrtf(red[2] + red[5]), EPS);
        out[g] = num / (na * nb);
    }
}

// ---------------- fallback: verified fp32 single-kernel version (52.8 us) ----------------
__global__ __launch_bounds__(128) void rgcn_fused_kernel(
    const float* __restrict__ x, const float* __restrict__ basis,
    const float* __restrict__ root, const float* __restrict__ bias,
    const float* __restrict__ target, const int* __restrict__ edge_index,
    const int* __restrict__ edge_type, float* __restrict__ out)
{
    const int g = blockIdx.x;
    const int o = threadIdx.x;
    __shared__ float xs[NPG][DIM];
    __shared__ float red[6];
    {
        const float4* xg = reinterpret_cast<const float4*>(x + (size_t)g * NPG * DIM);
        float4* xs4 = reinterpret_cast<float4*>(&xs[0][0]);
        xs4[o] = xg[o];
        xs4[o + 128] = xg[o + 128];
    }
    __syncthreads();
    float acc[NPG];
    const float b = bias[o];
    #pragma unroll
    for (int n = 0; n < NPG; ++n) acc[n] = b;
    for (int d4 = 0; d4 < DIM / 4; ++d4) {
        const float r0 = root[(d4 * 4 + 0) * DIM + o];
        const float r1 = root[(d4 * 4 + 1) * DIM + o];
        const float r2 = root[(d4 * 4 + 2) * DIM + o];
        const float r3 = root[(d4 * 4 + 3) * DIM + o];
        #pragma unroll
        for (int n = 0; n < NPG; ++n) {
            const float4 xv = reinterpret_cast<const float4*>(&xs[n][0])[d4];
            acc[n] += xv.x * r0 + xv.y * r1 + xv.z * r2 + xv.w * r3;
        }
    }
    const int ebase = g * EPG;
    for (int e = 0; e < EPG; ++e) {
        const int ge  = ebase + e;
        const int src = edge_index[ge] - g * NPG;
        const int dst = edge_index[NUM_EDGES + ge] - g * NPG;
        const int rel = edge_type[ge];
        const float* __restrict__ B = basis + (size_t)rel * DIM * DIM;
        float m = 0.f;
        for (int d4 = 0; d4 < DIM / 4; ++d4) {
            const float4 xv = reinterpret_cast<const float4*>(&xs[src][0])[d4];
            m += xv.x * B[(d4 * 4 + 0) * DIM + o];
            m += xv.y * B[(d4 * 4 + 1) * DIM + o];
            m += xv.z * B[(d4 * 4 + 2) * DIM + o];
            m += xv.w * B[(d4 * 4 + 3) * DIM + o];
        }
        #pragma unroll
        for (int n = 0; n < NPG; ++n) acc[n] += (n == dst) ? m : 0.f;
    }
    float p = 0.f;
    #pragma unroll
    for (int n = 0; n < NPG; ++n) p += fmaxf(acc[n], 0.f);
    const float t = target[(size_t)g * DIM + o];
    float num_p = p * t, na_p = p * p, nb_p = t * t;
    #pragma unroll
    for (int off = 32; off > 0; off >>= 1) {
        num_p += __shfl_down(num_p, off);
        na_p  += __shfl_down(na_p, off);
        nb_p  += __shfl_down(nb_p, off);
    }
    const int wave = o >> 6, lane = o & 63;
    if (lane == 0) {
        red[wave * 3 + 0] = num_p;
        red[wave * 3 + 1] = na_p;
        red[wave * 3 + 2] = nb_p;
    }
    __syncthreads();
    if (o == 0) {
        const float num = red[0] + red[3];
        const float na  = fmaxf(sqrtf(red[1] + red[4]), EPS);
        const float nb  = fmaxf(sqrtf(red[2] + red[5]), EPS);
        out[g] = num / (na * nb);
    }
}

extern "C" void kernel_launch(void* const* d_in, const int* in_sizes, int n_in,
                              void* d_out, int out_size, void* d_ws, size_t ws_size,
                              hipStream_t stream) {
    const float* x          = (const float*)d_in[0];
    const float* basis      = (const float*)d_in[1];
    const float* root       = (const float*)d_in[2];
    const float* bias       = (const float*)d_in[3];
    const float* target     = (const float*)d_in[4];
    const int*   edge_index = (const int*)d_in[5];
    const int*   edge_type  = (const int*)d_in[6];
    float* out = (float*)d_out;

    if (ws_size < WS_NEEDED) {
        rgcn_fused_kernel<<<BATCH, 128, 0, stream>>>(
            x, basis, root, bias, target, edge_index, edge_type, out);
        return;
    }

    char* ws = (char*)d_ws;
    _Float16* xh     = (_Float16*)(ws + XH_OFF);
    _Float16* Bh     = (_Float16*)(ws + BH_OFF);
    int*      cnt    = (int*)(ws + CNT_OFF);
    int*      elist  = (int*)(ws + EL_OFF);
    _Float16* msg_h  = (_Float16*)(ws + MSG_OFF);
    _Float16* rootp_h= (_Float16*)(ws + RTP_OFF);

    cvt_x_kernel<<<(NUM_NODES * DIM / 8) / 256, 256, 0, stream>>>(x, xh);
    pack_b_kernel<<<NUM_RELS + 1, 256, 0, stream>>>(basis, root, Bh);
    build_lists_kernel<<<NUM_RELS, 256, 0, stream>>>(edge_type, cnt, elist);
    gemm_kernel<<<EDGE_BLOCKS + ROOT_BLOCKS, 256, 0, stream>>>(
        xh, Bh, edge_index, cnt, elist, msg_h, rootp_h);
    finalize_kernel<<<BATCH, 128, 0, stream>>>(
        rootp_h, msg_h, bias, target, edge_index, out);
}

// Round 8
// 36.781 us; speedup vs baseline: 1.8449x; 1.3746x over previous
//
#include <hip/hip_runtime.h>

#define NUM_NODES 16384
#define NPG 8
#define NUM_EDGES 14336
#define EPG 7
#define NUM_RELS 64
#define DIM 128
#define BATCH 2048
#define EPS 1e-8f

#define CAP 512                      // max edges/relation (mean 224, sd ~15)
#define EDGE_BLOCKS (NUM_RELS * 8)   // 8 parts x 64 rows
#define ROOT_BLOCKS (NUM_NODES / 64) // 256

// prep grid layout
#define CVT_BLOCKS 256               // 65536 threads x 8 float4 = all of x
#define PACK_B0 CVT_BLOCKS           // 65 blocks (rel 64 = root)
#define LIST_B0 (PACK_B0 + NUM_RELS + 1)
#define PREP_BLOCKS (LIST_B0 + NUM_RELS)   // 385

using f16x4 = __attribute__((ext_vector_type(4))) _Float16;
using f16x8 = __attribute__((ext_vector_type(8))) _Float16;
using f32x4 = __attribute__((ext_vector_type(4))) float;

// ---- ws layout (bytes) ----
#define XH_OFF  0u
#define BH_OFF  4194304u                  // xh: 16384*128*2
#define CNT_OFF 6324224u                  // Bh: 65*128*128*2
#define EL_OFF  6324480u
#define MSG_OFF 6455552u                  // elist: 64*512*4
#define RTP_OFF 10125568u                 // msg_h: 14336*128*2
#define WS_NEEDED 14319872u               // rootp_h: 16384*128*2

#define TL_STRIDE 130   // padded f16 stride (65 dwords, odd) -> conflict-reduced transpose

// ---------------- kernel 1: prep = cvt_x | pack_b | build_lists ----------------
__global__ __launch_bounds__(256) void prep_kernel(
    const float* __restrict__ x, const float* __restrict__ basis,
    const float* __restrict__ root, const int* __restrict__ edge_type,
    _Float16* __restrict__ xh, _Float16* __restrict__ Bh,
    int* __restrict__ cnt, int* __restrict__ elist)
{
    __shared__ _Float16 Tl[DIM * TL_STRIDE];   // 33280 B (pack region)
    __shared__ int lcnt;                       // lists region
    const int b = blockIdx.x;
    const int tid = threadIdx.x;

    if (b < CVT_BLOCKS) {
        // ---- x fp32 -> fp16: 524288 float4, 65536 threads, 8 each, fully coalesced
        const int t = b * 256 + tid;
        const float4* xin = (const float4*)x;
        #pragma unroll
        for (int k = 0; k < 8; ++k) {
            const int i = k * (CVT_BLOCKS * 256) + t;
            const float4 v = xin[i];
            f16x4 o;
            o[0] = (_Float16)v.x; o[1] = (_Float16)v.y;
            o[2] = (_Float16)v.z; o[3] = (_Float16)v.w;
            *(f16x4*)(xh + (size_t)i * 4) = o;
        }
    } else if (b < LIST_B0) {
        // ---- pack basis/root fp32 [d][o] -> fp16 col-major [o][d]
        const int r = b - PACK_B0;               // 0..64
        const float* src = (r < NUM_RELS) ? (basis + ((size_t)r << 14)) : root;
        #pragma unroll
        for (int i = 0; i < 8; ++i) {
            int g8 = i * 256 + tid;              // 2048 groups of 8 f32, row-major
            int row = g8 >> 4;
            int col = (g8 & 15) * 8;
            const float4 a = ((const float4*)src)[g8 * 2];
            const float4 bb = ((const float4*)src)[g8 * 2 + 1];
            f16x8 o;
            o[0] = (_Float16)a.x;  o[1] = (_Float16)a.y;  o[2] = (_Float16)a.z;  o[3] = (_Float16)a.w;
            o[4] = (_Float16)bb.x; o[5] = (_Float16)bb.y; o[6] = (_Float16)bb.z; o[7] = (_Float16)bb.w;
            *(f16x8*)(&Tl[row * TL_STRIDE + col]) = o;
        }
        __syncthreads();
        #pragma unroll
        for (int i = 0; i < 8; ++i) {
            int chunk = i * 256 + tid;           // (o, db): 8 d-values of column o
            int o = chunk >> 4;
            int db = chunk & 15;
            f16x8 v;
            #pragma unroll
            for (int u = 0; u < 8; ++u) v[u] = Tl[(db * 8 + u) * TL_STRIDE + o];
            *(f16x8*)(Bh + ((size_t)r << 14) + o * DIM + db * 8) = v;
        }
    } else {
        // ---- bucket edges by relation
        const int r = b - LIST_B0;               // 0..63
        if (tid == 0) lcnt = 0;
        __syncthreads();
        for (int e = tid; e < NUM_EDGES; e += 256) {
            if (edge_type[e] == r) {
                int p = atomicAdd(&lcnt, 1);
                if (p < CAP) elist[r * CAP + p] = e;
            }
        }
        __syncthreads();
        if (tid == 0) cnt[r] = min(lcnt, CAP);
    }
}

// ---------------- kernel 2: MFMA GEMM (edge msgs + root) ----------------
// Identical to the verified R7 kernel. Block: 4 waves, one 64-row strip.
// B (128x128 f16 col-major [col][k]) staged in LDS with 16B-chunk XOR swizzle.
__global__ __launch_bounds__(256) void gemm_kernel(
    const _Float16* __restrict__ xh, const _Float16* __restrict__ Bh,
    const int* __restrict__ edge_index,
    const int* __restrict__ cnt, const int* __restrict__ elist,
    _Float16* __restrict__ msg_h, _Float16* __restrict__ rootp_h)
{
    __shared__ _Float16 Bl[DIM * DIM];   // 32 KB
    __shared__ int smeta[128];

    const int bid = blockIdx.x;
    const int tid = threadIdx.x;
    const bool isEdge = bid < EDGE_BLOCKS;
    const _Float16* Bg;

    if (isEdge) {
        const int rel = bid >> 3;
        const int part = bid & 7;
        const int c = cnt[rel];
        const int row0 = part * 64;
        if (row0 >= c) return;           // block-uniform exit before barrier
        Bg = Bh + ((size_t)rel << 14);
        if (tid < 64) {
            int j = row0 + tid;
            if (j < c) {
                int e = elist[rel * CAP + j];
                smeta[tid] = edge_index[e];
                smeta[64 + tid] = e;
            } else {
                smeta[tid] = 0;
                smeta[64 + tid] = -1;
            }
        }
    } else {
        const int row0 = (bid - EDGE_BLOCKS) * 64;
        Bg = Bh + ((size_t)NUM_RELS << 14);
        if (tid < 64) {
            smeta[tid] = row0 + tid;
            smeta[64 + tid] = row0 + tid;
        }
    }

    #pragma unroll
    for (int i = 0; i < 8; ++i) {
        int c16 = i * 256 + tid;
        int cs = c16 ^ ((c16 >> 4) & 7);
        *(f16x8*)(&Bl[cs * 8]) = *(const f16x8*)(Bg + c16 * 8);
    }
    __syncthreads();

    const int lane = tid & 63;
    const int w = tid >> 6;
    const int l15 = lane & 15;
    const int q = lane >> 4;

    const int src = smeta[w * 16 + l15];
    const _Float16* xrow = xh + ((size_t)src << 7) + q * 8;
    f16x8 a[4];
    #pragma unroll
    for (int kb = 0; kb < 4; ++kb) a[kb] = *(const f16x8*)(xrow + kb * 32);

    f32x4 acc[8];
    #pragma unroll
    for (int ct = 0; ct < 8; ++ct) acc[ct] = (f32x4){0.f, 0.f, 0.f, 0.f};

    #pragma unroll
    for (int ct = 0; ct < 8; ++ct) {
        const int col = ct * 16 + l15;
        #pragma unroll
        for (int kb = 0; kb < 4; ++kb) {
            int chunk = col * 16 + kb * 4 + q;
            int cs = chunk ^ (col & 7);
            f16x8 bfr = *(const f16x8*)(&Bl[cs * 8]);
            acc[ct] = __builtin_amdgcn_mfma_f32_16x16x32_f16(a[kb], bfr, acc[ct], 0, 0, 0);
        }
    }

    _Float16* outb = isEdge ? msg_h : rootp_h;
    #pragma unroll
    for (int j = 0; j < 4; ++j) {
        const int r = w * 16 + q * 4 + j;
        const int oid = smeta[64 + r];
        if (oid >= 0) {
            #pragma unroll
            for (int ct = 0; ct < 8; ++ct) {
                outb[((size_t)oid << 7) + ct * 16 + l15] = (_Float16)acc[ct][j];
            }
        }
    }
}

// ---------------- kernel 3: finalize, wave-per-graph ----------------
// 256 thr = 4 waves = 4 graphs. Lane l owns dims (2l, 2l+1): f16x2 loads = full
// 256B/wave transactions; shfl-only reduction, no LDS, no barriers.
__global__ __launch_bounds__(256) void finalize_kernel(
    const _Float16* __restrict__ rootp_h, const _Float16* __restrict__ msg_h,
    const float* __restrict__ bias, const float* __restrict__ target,
    const int* __restrict__ edge_index, float* __restrict__ out)
{
    const int g = blockIdx.x * 4 + (threadIdx.x >> 6);
    const int l = threadIdx.x & 63;
    const int d0 = l * 2;

    const float2 bv = *(const float2*)(bias + d0);
    float accA[NPG], accB[NPG];
    #pragma unroll
    for (int n = 0; n < NPG; ++n) {
        const f16x4* rp = (const f16x4*)nullptr;  // (unused type anchor)
        const _Float16* row = rootp_h + ((size_t)(g * NPG + n) << 7) + d0;
        accA[n] = bv.x + (float)row[0];
        accB[n] = bv.y + (float)row[1];
        (void)rp;
    }

    const int ebase = g * EPG;
    #pragma unroll
    for (int e = 0; e < EPG; ++e) {
        const int ge  = ebase + e;
        const int dst = edge_index[NUM_EDGES + ge] - g * NPG;
        const _Float16* mrow = msg_h + ((size_t)ge << 7) + d0;
        const float m0 = (float)mrow[0];
        const float m1 = (float)mrow[1];
        #pragma unroll
        for (int n = 0; n < NPG; ++n) {
            accA[n] += (n == dst) ? m0 : 0.f;
            accB[n] += (n == dst) ? m1 : 0.f;
        }
    }

    float p0 = 0.f, p1 = 0.f;
    #pragma unroll
    for (int n = 0; n < NPG; ++n) {
        p0 += fmaxf(accA[n], 0.f);
        p1 += fmaxf(accB[n], 0.f);
    }

    const float2 tv = *(const float2*)(target + (size_t)g * DIM + d0);
    float num_p = p0 * tv.x + p1 * tv.y;
    float na_p  = p0 * p0 + p1 * p1;
    float nb_p  = tv.x * tv.x + tv.y * tv.y;

    #pragma unroll
    for (int off = 32; off > 0; off >>= 1) {
        num_p += __shfl_down(num_p, off);
        na_p  += __shfl_down(na_p, off);
        nb_p  += __shfl_down(nb_p, off);
    }
    if (l == 0) {
        const float na = fmaxf(sqrtf(na_p), EPS);
        const float nb = fmaxf(sqrtf(nb_p), EPS);
        out[g] = num_p / (na * nb);
    }
}

// ---------------- fallback: verified fp32 single-kernel version (52.8 us) ----------------
__global__ __launch_bounds__(128) void rgcn_fused_kernel(
    const float* __restrict__ x, const float* __restrict__ basis,
    const float* __restrict__ root, const float* __restrict__ bias,
    const float* __restrict__ target, const int* __restrict__ edge_index,
    const int* __restrict__ edge_type, float* __restrict__ out)
{
    const int g = blockIdx.x;
    const int o = threadIdx.x;
    __shared__ float xs[NPG][DIM];
    __shared__ float red[6];
    {
        const float4* xg = reinterpret_cast<const float4*>(x + (size_t)g * NPG * DIM);
        float4* xs4 = reinterpret_cast<float4*>(&xs[0][0]);
        xs4[o] = xg[o];
        xs4[o + 128] = xg[o + 128];
    }
    __syncthreads();
    float acc[NPG];
    const float b = bias[o];
    #pragma unroll
    for (int n = 0; n < NPG; ++n) acc[n] = b;
    for (int d4 = 0; d4 < DIM / 4; ++d4) {
        const float r0 = root[(d4 * 4 + 0) * DIM + o];
        const float r1 = root[(d4 * 4 + 1) * DIM + o];
        const float r2 = root[(d4 * 4 + 2) * DIM + o];
        const float r3 = root[(d4 * 4 + 3) * DIM + o];
        #pragma unroll
        for (int n = 0; n < NPG; ++n) {
            const float4 xv = reinterpret_cast<const float4*>(&xs[n][0])[d4];
            acc[n] += xv.x * r0 + xv.y * r1 + xv.z * r2 + xv.w * r3;
        }
    }
    const int ebase = g * EPG;
    for (int e = 0; e < EPG; ++e) {
        const int ge  = ebase + e;
        const int src = edge_index[ge] - g * NPG;
        const int dst = edge_index[NUM_EDGES + ge] - g * NPG;
        const int rel = edge_type[ge];
        const float* __restrict__ B = basis + (size_t)rel * DIM * DIM;
        float m = 0.f;
        for (int d4 = 0; d4 < DIM / 4; ++d4) {
            const float4 xv = reinterpret_cast<const float4*>(&xs[src][0])[d4];
            m += xv.x * B[(d4 * 4 + 0) * DIM + o];
            m += xv.y * B[(d4 * 4 + 1) * DIM + o];
            m += xv.z * B[(d4 * 4 + 2) * DIM + o];
            m += xv.w * B[(d4 * 4 + 3) * DIM + o];
        }
        #pragma unroll
        for (int n = 0; n < NPG; ++n) acc[n] += (n == dst) ? m : 0.f;
    }
    float p = 0.f;
    #pragma unroll
    for (int n = 0; n < NPG; ++n) p += fmaxf(acc[n], 0.f);
    const float t = target[(size_t)g * DIM + o];
    float num_p = p * t, na_p = p * p, nb_p = t * t;
    #pragma unroll
    for (int off = 32; off > 0; off >>= 1) {
        num_p += __shfl_down(num_p, off);
        na_p  += __shfl_down(na_p, off);
        nb_p  += __shfl_down(nb_p, off);
    }
    const int wave = o >> 6, lane = o & 63;
    if (lane == 0) {
        red[wave * 3 + 0] = num_p;
        red[wave * 3 + 1] = na_p;
        red[wave * 3 + 2] = nb_p;
    }
    __syncthreads();
    if (o == 0) {
        const float num = red[0] + red[3];
        const float na  = fmaxf(sqrtf(red[1] + red[4]), EPS);
        const float nb  = fmaxf(sqrtf(red[2] + red[5]), EPS);
        out[g] = num / (na * nb);
    }
}

extern "C" void kernel_launch(void* const* d_in, const int* in_sizes, int n_in,
                              void* d_out, int out_size, void* d_ws, size_t ws_size,
                              hipStream_t stream) {
    const float* x          = (const float*)d_in[0];
    const float* basis      = (const float*)d_in[1];
    const float* root       = (const float*)d_in[2];
    const float* bias       = (const float*)d_in[3];
    const float* target     = (const float*)d_in[4];
    const int*   edge_index = (const int*)d_in[5];
    const int*   edge_type  = (const int*)d_in[6];
    float* out = (float*)d_out;

    if (ws_size < WS_NEEDED) {
        rgcn_fused_kernel<<<BATCH, 128, 0, stream>>>(
            x, basis, root, bias, target, edge_index, edge_type, out);
        return;
    }

    char* ws = (char*)d_ws;
    _Float16* xh      = (_Float16*)(ws + XH_OFF);
    _Float16* Bh      = (_Float16*)(ws + BH_OFF);
    int*      cnt     = (int*)(ws + CNT_OFF);
    int*      elist   = (int*)(ws + EL_OFF);
    _Float16* msg_h   = (_Float16*)(ws + MSG_OFF);
    _Float16* rootp_h = (_Float16*)(ws + RTP_OFF);

    prep_kernel<<<PREP_BLOCKS, 256, 0, stream>>>(
        x, basis, root, edge_type, xh, Bh, cnt, elist);
    gemm_kernel<<<EDGE_BLOCKS + ROOT_BLOCKS, 256, 0, stream>>>(
        xh, Bh, edge_index, cnt, elist, msg_h, rootp_h);
    finalize_kernel<<<BATCH / 4, 256, 0, stream>>>(
        rootp_h, msg_h, bias, target, edge_index, out);
}